// Round 13
// baseline (124.101 us; speedup 1.0000x reference)
//
#include <hip/hip_runtime.h>

#define NSET 48
#define NITEM 128
#define DIM 256
#define HEADS 4
#define NROWS (NSET * NITEM)   // 6144 rows per source

typedef _Float16 f16;
typedef _Float16 f16x8 __attribute__((ext_vector_type(8)));
typedef _Float16 f16x4 __attribute__((ext_vector_type(4)));
typedef float    f32x4 __attribute__((ext_vector_type(4)));

// ---- fragment-major layout ----
// A source matrix is stored per 128-row "set" (32768 halves = 64KB). Within a
// set: 64 chunks of 512 halves (1KB), chunk = (r/16)*8 + (k/32). Within a
// chunk, lane-slot l (16B) holds row r = rbase+(l&15), halves kbase+(l>>4)*8..+8
// -- exactly the mfma_16x16x32 A/B fragment for that (row-block, k-block).
// One operand fragment load = ONE lane-contiguous 1KB wave-load (R5 lesson:
// row-major fragment loads cost 16 L1 transactions per instruction).
#define SETH 32768   // halves per set
__device__ __forceinline__ int faddr(int r, int k) {   // in halves, within a set
  return ((r >> 4) * 8 + (k >> 5)) * 512 + ((((k >> 3) & 3) * 16 + (r & 15)) * 8) + (k & 7);
}

// ---- workspace layout (bytes) ----
static constexpr size_t OFF_XYH = 6291456;
static constexpr size_t OFF_WT  = 12582912;
static constexpr size_t OFF_LXY = 12713984;

// ---------------- prep: row l2-normalize + fp16 casts + W^T (fused) ----------------
__global__ __launch_bounds__(256) void k_norm(const float* __restrict__ x,
                                              const float* __restrict__ y,
                                              const float* __restrict__ W,
                                              f16* __restrict__ XYN_F,
                                              f16* __restrict__ XYH_F,
                                              f16* __restrict__ WT_F) {
  int rg   = blockIdx.x * 4 + (threadIdx.x >> 6);   // global row 0..12287
  int lane = threadIdx.x & 63;
  const float* src = (rg < NROWS) ? (x + (size_t)rg * DIM)
                                  : (y + (size_t)(rg - NROWS) * DIM);
  float4 v = *(const float4*)(src + lane * 4);
  float ss = v.x * v.x + v.y * v.y + v.z * v.z + v.w * v.w;
  #pragma unroll
  for (int off = 32; off >= 1; off >>= 1) ss += __shfl_xor(ss, off);
  float rn = 1.0f / sqrtf(fmaxf(ss, 1e-12f));       // tf.nn.l2_normalize semantics
  f16x4 hn = { (f16)(v.x * rn), (f16)(v.y * rn), (f16)(v.z * rn), (f16)(v.w * rn) };
  f16x4 hr = { (f16)v.x, (f16)v.y, (f16)v.z, (f16)v.w };
  int dst = (rg >> 7) * SETH + faddr(rg & 127, lane * 4);   // 8B slot
  *(f16x4*)(XYN_F + dst) = hn;
  *(f16x4*)(XYH_F + dst) = hr;
  // fused W^T (saves a launch): first 256 blocks also transpose one W row
  if (blockIdx.x < 256) {
    int d = blockIdx.x, c = threadIdx.x;
    WT_F[(c >> 7) * SETH + faddr(c & 127, d)] = (f16)W[d * DIM + c];
  }
}

// ---------------- prep: projection GEMM  LXY[R][c] = XYH[R][:] . WT[c][:] ----------------
__global__ __launch_bounds__(256, 2) void k_proj(const f16* __restrict__ XYH_F,
                                                 const f16* __restrict__ WT_F,
                                                 f16* __restrict__ LXY_F) {
  const int bid = blockIdx.x, rt = bid >> 1, ct = bid & 1;   // 96 row-sets x 2 col-tiles
  const int tid = threadIdx.x, w = tid >> 6, lane = tid & 63;
  const int wR = (w >> 1) * 64;        // R range within set
  const int wC = (w & 1) * 64;         // c range within 128-col tile
  const int la = lane & 15, lb = lane >> 4;

  const f16* pa[4];                    // A = WT rows (c), set ct
  const f16* pb[4];                    // B = XYH rows (R), set rt
  #pragma unroll
  for (int m = 0; m < 4; ++m)
    pa[m] = WT_F + ct * SETH + ((wC >> 4) + m) * 4096 + lane * 8;
  #pragma unroll
  for (int n = 0; n < 4; ++n)
    pb[n] = XYH_F + rt * SETH + ((wR >> 4) + n) * 4096 + lane * 8;

  f32x4 acc[4][4] = {};
  #pragma unroll
  for (int k0 = 0; k0 < DIM; k0 += 32) {
    const int ko = (k0 >> 5) * 512;
    f16x8 a[4], b[4];
    #pragma unroll
    for (int m = 0; m < 4; ++m) a[m] = *(const f16x8*)(pa[m] + ko);
    #pragma unroll
    for (int n = 0; n < 4; ++n) b[n] = *(const f16x8*)(pb[n] + ko);
    #pragma unroll
    for (int m = 0; m < 4; ++m)
      #pragma unroll
      for (int n = 0; n < 4; ++n)
        acc[m][n] = __builtin_amdgcn_mfma_f32_16x16x32_f16(a[m], b[n], acc[m][n], 0, 0, 0);
  }
  // D[row=c][col=R]: lane holds 4 consecutive c at fixed R -> 8B frag-major write
  #pragma unroll
  for (int m = 0; m < 4; ++m)
    #pragma unroll
    for (int n = 0; n < 4; ++n) {
      int rloc = wR + n * 16 + la;               // R within set rt
      int c0   = ct * 128 + wC + m * 16 + lb * 4;
      f16x4 hv = { (f16)acc[m][n][0], (f16)acc[m][n][1],
                   (f16)acc[m][n][2], (f16)acc[m][n][3] };
      *(f16x4*)(LXY_F + rt * SETH + faddr(rloc, c0)) = hv;
    }
}

// ---------------- main: union-grid cos|score, one 8-wave block per tile ----------------
// R13: grid-level fusion. Even blocks do a cos tile, odd blocks a score tile
// (same (ys,xs) pair = bid>>1). Each block runs ONE phase -> register budget
// = max(paths) (~100, no spill; intra-block fusion spilled in R4/R8). The CU
// scheduler co-resides store-heavy cos blocks with load/MFMA-heavy score
// blocks, filling each other's latency bubbles; one launch boundary gone.
// (512,4): 8 waves/block, 64x32 per-wave tile (acc=32 VGPR), 16 waves/CU.
__global__ __launch_bounds__(512, 4) void k_main(const f16* __restrict__ XYN_F,
                                                 const f16* __restrict__ LXY_F,
                                                 const float* __restrict__ nItem,
                                                 const float* __restrict__ w2,
                                                 float* __restrict__ out0,
                                                 float* __restrict__ out1) {
  __shared__ float red[8][HEADS];
  const int bid = blockIdx.x;
  const int pair = bid >> 1;
  const int ys = pair / NSET, xs = pair % NSET;
  const int tid = threadIdx.x, w = tid >> 6, lane = tid & 63;
  const int wj = (w >> 1) * 32;        // j (y item) range -> A operand, 2 tiles
  const int wi = (w & 1) * 64;         // i (x item) range -> B operand, 4 tiles
  const int la = lane & 15, lb = lane >> 4;

  if ((bid & 1) == 0) {
    // ---- cos path: direct nt stores, no LDS, no barriers ----
    const f16* pa[2];
    const f16* pb[4];
    #pragma unroll
    for (int m = 0; m < 2; ++m)
      pa[m] = XYN_F + (48 + ys) * SETH + ((wj >> 4) + m) * 4096 + lane * 8;
    #pragma unroll
    for (int n = 0; n < 4; ++n)
      pb[n] = XYN_F + xs * SETH + ((wi >> 4) + n) * 4096 + lane * 8;

    f32x4 acc[2][4] = {};
    #pragma unroll
    for (int k0 = 0; k0 < DIM; k0 += 32) {
      const int ko = (k0 >> 5) * 512;
      f16x8 a[2], b[4];
      #pragma unroll
      for (int m = 0; m < 2; ++m) a[m] = *(const f16x8*)(pa[m] + ko);
      #pragma unroll
      for (int n = 0; n < 4; ++n) b[n] = *(const f16x8*)(pb[n] + ko);
      #pragma unroll
      for (int m = 0; m < 2; ++m)
        #pragma unroll
        for (int n = 0; n < 4; ++n)
          acc[m][n] = __builtin_amdgcn_mfma_f32_16x16x32_f16(a[m], b[n], acc[m][n], 0, 0, 0);
    }

    // D[row=j][col=i]; out0[ys][xs][i][j]: lane stores f32x4 at i*128+j0
    float* base = out0 + (size_t)(ys * NSET + xs) * NITEM * NITEM;
    #pragma unroll
    for (int n = 0; n < 4; ++n) {
      int i = wi + n * 16 + la;
      #pragma unroll
      for (int m = 0; m < 2; ++m) {
        int j0 = wj + m * 16 + lb * 4;
        __builtin_nontemporal_store(acc[m][n], (f32x4*)(base + (size_t)i * NITEM + j0));
      }
    }
  } else {
    // ---- score path ----
    const f16* pa[2];
    const f16* pb[4];
    #pragma unroll
    for (int m = 0; m < 2; ++m)
      pa[m] = LXY_F + (48 + ys) * SETH + ((wj >> 4) + m) * 4096 + lane * 8;
    #pragma unroll
    for (int n = 0; n < 4; ++n)
      pb[n] = LXY_F + xs * SETH + ((wi >> 4) + n) * 4096 + lane * 8;

    float rsum[HEADS];
    #pragma unroll
    for (int h = 0; h < HEADS; ++h) {
      f32x4 acc[2][4] = {};
      #pragma unroll
      for (int kk = 0; kk < 2; ++kk) {           // K=64 per head; relu AFTER full K
        const int ko = (h * 2 + kk) * 512;
        f16x8 a[2], b[4];
        #pragma unroll
        for (int m = 0; m < 2; ++m) a[m] = *(const f16x8*)(pa[m] + ko);
        #pragma unroll
        for (int n = 0; n < 4; ++n) b[n] = *(const f16x8*)(pb[n] + ko);
        #pragma unroll
        for (int m = 0; m < 2; ++m)
          #pragma unroll
          for (int n = 0; n < 4; ++n)
            acc[m][n] = __builtin_amdgcn_mfma_f32_16x16x32_f16(a[m], b[n], acc[m][n], 0, 0, 0);
      }
      float s = 0.f;
      #pragma unroll
      for (int m = 0; m < 2; ++m)
        #pragma unroll
        for (int n = 0; n < 4; ++n)
          #pragma unroll
          for (int r = 0; r < 4; ++r) s += fmaxf(acc[m][n][r], 0.f);
      rsum[h] = s;
    }
    #pragma unroll
    for (int off = 32; off >= 1; off >>= 1)
      #pragma unroll
      for (int h = 0; h < HEADS; ++h) rsum[h] += __shfl_xor(rsum[h], off);
    if (lane == 0) {
      #pragma unroll
      for (int h = 0; h < HEADS; ++h) red[w][h] = rsum[h];
    }
    __syncthreads();
    if (tid == 0) {
      // relu(S/8) summed == (sum relu(S))/8 ; / nItem[x] / nItem[y]; @ w2
      float inv = 1.0f / (8.0f * nItem[xs] * nItem[ys]);
      float sc = 0.f;
      #pragma unroll
      for (int h = 0; h < HEADS; ++h) {
        float t = 0.f;
        #pragma unroll
        for (int ww = 0; ww < 8; ++ww) t += red[ww][h];
        sc += t * inv * w2[h];
      }
      out1[ys * NSET + xs] = sc;
    }
  }
}

// ---------------- launch ----------------
extern "C" void kernel_launch(void* const* d_in, const int* in_sizes, int n_in,
                              void* d_out, int out_size, void* d_ws, size_t ws_size,
                              hipStream_t stream) {
  const float* x     = (const float*)d_in[0];
  const float* y     = (const float*)d_in[1];
  const float* nItem = (const float*)d_in[2];
  const float* W     = (const float*)d_in[3];
  const float* w2    = (const float*)d_in[4];
  float* out0 = (float*)d_out;
  float* out1 = out0 + (size_t)NSET * NSET * NITEM * NITEM;

  char* ws = (char*)d_ws;
  f16* XYN_F = (f16*)ws;
  f16* XYH_F = (f16*)(ws + OFF_XYH);
  f16* WT_F  = (f16*)(ws + OFF_WT);
  f16* LXY_F = (f16*)(ws + OFF_LXY);

  k_norm<<<(2 * NROWS) / 4, 256, 0, stream>>>(x, y, W, XYN_F, XYH_F, WT_F);
  k_proj<<<192, 256, 0, stream>>>(XYH_F, WT_F, LXY_F);
  k_main<<<2 * NSET * NSET, 512, 0, stream>>>(XYN_F, LXY_F, nItem, w2, out0, out1);
}

// Round 14
// 110.400 us; speedup vs baseline: 1.1241x; 1.1241x over previous
//
#include <hip/hip_runtime.h>

#define NSET 48
#define NITEM 128
#define DIM 256
#define HEADS 4
#define NROWS (NSET * NITEM)   // 6144 rows per source

typedef _Float16 f16;
typedef _Float16 f16x8 __attribute__((ext_vector_type(8)));
typedef _Float16 f16x4 __attribute__((ext_vector_type(4)));
typedef float    f32x4 __attribute__((ext_vector_type(4)));

// ---- fragment-major layout ----
// A source matrix is stored per 128-row "set" (32768 halves = 64KB). Within a
// set: 64 chunks of 512 halves (1KB), chunk = (r/16)*8 + (k/32). Within a
// chunk, lane-slot l (16B) holds row r = rbase+(l&15), halves kbase+(l>>4)*8..+8
// -- exactly the mfma_16x16x32 A/B fragment for that (row-block, k-block).
// One operand fragment load = ONE lane-contiguous 1KB wave-load (R5 lesson:
// row-major fragment loads cost 16 L1 transactions per instruction).
#define SETH 32768   // halves per set
__device__ __forceinline__ int faddr(int r, int k) {   // in halves, within a set
  return ((r >> 4) * 8 + (k >> 5)) * 512 + ((((k >> 3) & 3) * 16 + (r & 15)) * 8) + (k & 7);
}

// ---- workspace layout (bytes) ----
static constexpr size_t OFF_XYH = 6291456;
static constexpr size_t OFF_WT  = 12582912;
static constexpr size_t OFF_LXY = 12713984;

// ---------------- prep: row l2-normalize + fp16 casts + W^T (fused) ----------------
__global__ __launch_bounds__(256) void k_norm(const float* __restrict__ x,
                                              const float* __restrict__ y,
                                              const float* __restrict__ W,
                                              f16* __restrict__ XYN_F,
                                              f16* __restrict__ XYH_F,
                                              f16* __restrict__ WT_F) {
  int rg   = blockIdx.x * 4 + (threadIdx.x >> 6);   // global row 0..12287
  int lane = threadIdx.x & 63;
  const float* src = (rg < NROWS) ? (x + (size_t)rg * DIM)
                                  : (y + (size_t)(rg - NROWS) * DIM);
  float4 v = *(const float4*)(src + lane * 4);
  float ss = v.x * v.x + v.y * v.y + v.z * v.z + v.w * v.w;
  #pragma unroll
  for (int off = 32; off >= 1; off >>= 1) ss += __shfl_xor(ss, off);
  float rn = 1.0f / sqrtf(fmaxf(ss, 1e-12f));       // tf.nn.l2_normalize semantics
  f16x4 hn = { (f16)(v.x * rn), (f16)(v.y * rn), (f16)(v.z * rn), (f16)(v.w * rn) };
  f16x4 hr = { (f16)v.x, (f16)v.y, (f16)v.z, (f16)v.w };
  int dst = (rg >> 7) * SETH + faddr(rg & 127, lane * 4);   // 8B slot
  *(f16x4*)(XYN_F + dst) = hn;
  *(f16x4*)(XYH_F + dst) = hr;
  // fused W^T (saves a launch): first 256 blocks also transpose one W row
  if (blockIdx.x < 256) {
    int d = blockIdx.x, c = threadIdx.x;
    WT_F[(c >> 7) * SETH + faddr(c & 127, d)] = (f16)W[d * DIM + c];
  }
}

// ---------------- prep: projection GEMM  LXY[R][c] = XYH[R][:] . WT[c][:] ----------------
__global__ __launch_bounds__(256, 2) void k_proj(const f16* __restrict__ XYH_F,
                                                 const f16* __restrict__ WT_F,
                                                 f16* __restrict__ LXY_F) {
  const int bid = blockIdx.x, rt = bid >> 1, ct = bid & 1;   // 96 row-sets x 2 col-tiles
  const int tid = threadIdx.x, w = tid >> 6, lane = tid & 63;
  const int wR = (w >> 1) * 64;        // R range within set
  const int wC = (w & 1) * 64;         // c range within 128-col tile
  const int la = lane & 15, lb = lane >> 4;

  const f16* pa[4];                    // A = WT rows (c), set ct
  const f16* pb[4];                    // B = XYH rows (R), set rt
  #pragma unroll
  for (int m = 0; m < 4; ++m)
    pa[m] = WT_F + ct * SETH + ((wC >> 4) + m) * 4096 + lane * 8;
  #pragma unroll
  for (int n = 0; n < 4; ++n)
    pb[n] = XYH_F + rt * SETH + ((wR >> 4) + n) * 4096 + lane * 8;

  f32x4 acc[4][4] = {};
  #pragma unroll
  for (int k0 = 0; k0 < DIM; k0 += 32) {
    const int ko = (k0 >> 5) * 512;
    f16x8 a[4], b[4];
    #pragma unroll
    for (int m = 0; m < 4; ++m) a[m] = *(const f16x8*)(pa[m] + ko);
    #pragma unroll
    for (int n = 0; n < 4; ++n) b[n] = *(const f16x8*)(pb[n] + ko);
    #pragma unroll
    for (int m = 0; m < 4; ++m)
      #pragma unroll
      for (int n = 0; n < 4; ++n)
        acc[m][n] = __builtin_amdgcn_mfma_f32_16x16x32_f16(a[m], b[n], acc[m][n], 0, 0, 0);
  }
  // D[row=c][col=R]: lane holds 4 consecutive c at fixed R -> 8B frag-major write
  #pragma unroll
  for (int m = 0; m < 4; ++m)
    #pragma unroll
    for (int n = 0; n < 4; ++n) {
      int rloc = wR + n * 16 + la;               // R within set rt
      int c0   = ct * 128 + wC + m * 16 + lb * 4;
      f16x4 hv = { (f16)acc[m][n][0], (f16)acc[m][n][1],
                   (f16)acc[m][n][2], (f16)acc[m][n][3] };
      *(f16x4*)(LXY_F + rt * SETH + faddr(rloc, c0)) = hv;
    }
}

// ---------------- cos_sim kernel: one 8-wave block per (ys,xs) ----------------
// R14: R12's 8-wave (512,4) structure + LDS full-line epilogue. R13's counters
// proved direct 64B-piece nt stores 2x-amplify WRITE (308MB vs 151MB): the two
// 64B halves of each 128B line come from different instructions and nt bypasses
// L2, so nothing merges them. Fix: stage the 128x128 f32 tile in LDS (64KB,
// swizzled, 0 conflicts measured R5/R6), one barrier, stream full 512B rows
// (4 full lines per nt instruction).
__global__ __launch_bounds__(512, 4) void k_cos(const f16* __restrict__ XYN_F,
                                                float* __restrict__ out0) {
  __shared__ float hbuf[128 * 128];    // 64KB full f32 tile; 2 blocks/CU -> 128KB
  const int bid = blockIdx.x;
  const int ys = bid / NSET, xs = bid % NSET;
  const int tid = threadIdx.x, w = tid >> 6, lane = tid & 63;
  const int wj = (w >> 1) * 32;        // j (y item) range -> A operand, 2 tiles
  const int wi = (w & 1) * 64;         // i (x item) range -> B operand, 4 tiles
  const int la = lane & 15, lb = lane >> 4;

  const f16* pa[2];
  const f16* pb[4];
  #pragma unroll
  for (int m = 0; m < 2; ++m)
    pa[m] = XYN_F + (48 + ys) * SETH + ((wj >> 4) + m) * 4096 + lane * 8;
  #pragma unroll
  for (int n = 0; n < 4; ++n)
    pb[n] = XYN_F + xs * SETH + ((wi >> 4) + n) * 4096 + lane * 8;

  f32x4 acc[2][4] = {};
  #pragma unroll
  for (int k0 = 0; k0 < DIM; k0 += 32) {
    const int ko = (k0 >> 5) * 512;
    f16x8 a[2], b[4];
    #pragma unroll
    for (int m = 0; m < 2; ++m) a[m] = *(const f16x8*)(pa[m] + ko);
    #pragma unroll
    for (int n = 0; n < 4; ++n) b[n] = *(const f16x8*)(pb[n] + ko);
    #pragma unroll
    for (int m = 0; m < 2; ++m)
      #pragma unroll
      for (int n = 0; n < 4; ++n)
        acc[m][n] = __builtin_amdgcn_mfma_f32_16x16x32_f16(a[m], b[n], acc[m][n], 0, 0, 0);
  }

  // stage tile in LDS (row=i, 512B rows, XOR-swizzled within row)
  #pragma unroll
  for (int n = 0; n < 4; ++n) {
    int i = wi + n * 16 + la;
    #pragma unroll
    for (int m = 0; m < 2; ++m) {
      int jb4 = (wj + m * 16 + lb * 4) * 4;      // byte offset along j
      *(f32x4*)((char*)hbuf + i * 512 + (jb4 ^ ((i & 15) << 4))) = acc[m][n];
    }
  }
  __syncthreads();
  // stream out: each wave 16 rows, 2 full 512B rows per nt instruction
  float* base = out0 + (size_t)(ys * NSET + xs) * NITEM * NITEM;
  #pragma unroll
  for (int c = 0; c < 8; ++c) {
    int il = w * 16 + c * 2 + (lane >> 5);
    int jb = (lane & 31) * 16;
    f32x4 v = *(const f32x4*)((char*)hbuf + il * 512 + (jb ^ ((il & 15) << 4)));
    __builtin_nontemporal_store(v, (f32x4*)(base + (size_t)il * NITEM) + (lane & 31));
  }
}

// ---------------- score kernel: one 8-wave block per (ys,xs) ---- (R12 form) ----
__global__ __launch_bounds__(512, 4) void k_score(const f16* __restrict__ LXY_F,
                                                  const float* __restrict__ nItem,
                                                  const float* __restrict__ w2,
                                                  float* __restrict__ out1) {
  __shared__ float red[8][HEADS];
  const int bid = blockIdx.x;
  const int ys = bid / NSET, xs = bid % NSET;
  const int tid = threadIdx.x, w = tid >> 6, lane = tid & 63;
  const int wj = (w >> 1) * 32;        // j (y item) range -> A operand, 2 tiles
  const int wi = (w & 1) * 64;         // i (x item) range -> B operand, 4 tiles

  const f16* pa[2];
  const f16* pb[4];
  #pragma unroll
  for (int m = 0; m < 2; ++m)
    pa[m] = LXY_F + (48 + ys) * SETH + ((wj >> 4) + m) * 4096 + lane * 8;
  #pragma unroll
  for (int n = 0; n < 4; ++n)
    pb[n] = LXY_F + xs * SETH + ((wi >> 4) + n) * 4096 + lane * 8;

  float rsum[HEADS];
  #pragma unroll
  for (int h = 0; h < HEADS; ++h) {
    f32x4 acc[2][4] = {};
    #pragma unroll
    for (int kk = 0; kk < 2; ++kk) {             // K=64 per head; relu AFTER full K
      const int ko = (h * 2 + kk) * 512;
      f16x8 a[2], b[4];
      #pragma unroll
      for (int m = 0; m < 2; ++m) a[m] = *(const f16x8*)(pa[m] + ko);
      #pragma unroll
      for (int n = 0; n < 4; ++n) b[n] = *(const f16x8*)(pb[n] + ko);
      #pragma unroll
      for (int m = 0; m < 2; ++m)
        #pragma unroll
        for (int n = 0; n < 4; ++n)
          acc[m][n] = __builtin_amdgcn_mfma_f32_16x16x32_f16(a[m], b[n], acc[m][n], 0, 0, 0);
    }
    float s = 0.f;
    #pragma unroll
    for (int m = 0; m < 2; ++m)
      #pragma unroll
      for (int n = 0; n < 4; ++n)
        #pragma unroll
        for (int r = 0; r < 4; ++r) s += fmaxf(acc[m][n][r], 0.f);
    rsum[h] = s;
  }
  #pragma unroll
  for (int off = 32; off >= 1; off >>= 1)
    #pragma unroll
    for (int h = 0; h < HEADS; ++h) rsum[h] += __shfl_xor(rsum[h], off);
  if (lane == 0) {
    #pragma unroll
    for (int h = 0; h < HEADS; ++h) red[w][h] = rsum[h];
  }
  __syncthreads();
  if (tid == 0) {
    // relu(S/8) summed == (sum relu(S))/8 ; then / nItem[x] / nItem[y]; then @ w2
    float inv = 1.0f / (8.0f * nItem[xs] * nItem[ys]);
    float sc = 0.f;
    #pragma unroll
    for (int h = 0; h < HEADS; ++h) {
      float t = 0.f;
      #pragma unroll
      for (int ww = 0; ww < 8; ++ww) t += red[ww][h];
      sc += t * inv * w2[h];
    }
    out1[ys * NSET + xs] = sc;
  }
}

// ---------------- launch ----------------
extern "C" void kernel_launch(void* const* d_in, const int* in_sizes, int n_in,
                              void* d_out, int out_size, void* d_ws, size_t ws_size,
                              hipStream_t stream) {
  const float* x     = (const float*)d_in[0];
  const float* y     = (const float*)d_in[1];
  const float* nItem = (const float*)d_in[2];
  const float* W     = (const float*)d_in[3];
  const float* w2    = (const float*)d_in[4];
  float* out0 = (float*)d_out;
  float* out1 = out0 + (size_t)NSET * NSET * NITEM * NITEM;

  char* ws = (char*)d_ws;
  f16* XYN_F = (f16*)ws;
  f16* XYH_F = (f16*)(ws + OFF_XYH);
  f16* WT_F  = (f16*)(ws + OFF_WT);
  f16* LXY_F = (f16*)(ws + OFF_LXY);

  k_norm<<<(2 * NROWS) / 4, 256, 0, stream>>>(x, y, W, XYN_F, XYH_F, WT_F);
  k_proj<<<192, 256, 0, stream>>>(XYH_F, WT_F, LXY_F);
  k_cos<<<NSET * NSET, 512, 0, stream>>>(XYN_F, out0);
  k_score<<<NSET * NSET, 512, 0, stream>>>(LXY_F, nItem, w2, out1);
}